// Round 10
// baseline (292.467 us; speedup 1.0000x reference)
//
#include <hip/hip_runtime.h>
#include <hip/hip_bf16.h>

// AdaptiveReLULayer: out[b,n,o] = leaky( sum_i x[b,n,i] * weight[idx[b],i,o] + bias[o], 0.2 )
// B=2048, N=256, IN=256, OUT=256, C=1024.  f32 I/O; bf16 MFMA, f32 accum.
//
// R12 vs R11 (248us, first real win: bank-conflicts->0 + nontemporal x/out):
// largest remaining non-minimal stream is w FABRIC traffic: R11's 64x256
// tiles read the full 256KB w panel 4x per batch = 2.1GB of L2/TCC reads
// (66% of fabric bytes) contending with the 1.07GB HBM stream. R12 halves
// it: tile = 128 rows x 256 o (grid 4096, 512 thr = 8 waves, wave = 16 rows).
//   * w fabric 2x/batch = 1.07GB (floor for 2 n-halves); x HBM still 1x.
//   * 2 blocks/CU kept (mutual overlap, R10 lesson): A panel 64KB +
//     SINGLE-buffered B tile 16KB = 80KB LDS.  2-phase rounds, T3-minimum:
//     issue B(t+1) loads BEFORE compute(t); flush after the read-barrier.
//   * zero-conflict bbyte B layout (R7-measured 0.0), R11 A layout,
//     nt x-loads / out-stores, XCD swizzle: n-twins of a batch adjacent ->
//     co-resident -> their w reads coincide in L2.
//   * MFMA:ds_read = 16:17 per round (one af reused by 16 col-frags).
// Pre-committed: VGPR must be <=128 with no scratch (launch_bounds(512,4));
// predicted dur 205-230 if fabric was the binder, ~flat if not.

#define BK 32

typedef __attribute__((ext_vector_type(8))) __bf16 bf16x8;
typedef __attribute__((ext_vector_type(4))) float f32x4;
typedef __attribute__((ext_vector_type(4))) unsigned int u32x4;
typedef __attribute__((ext_vector_type(2))) unsigned int u32x2;

#define B_LDS 65536   // B^T tile base (A panel occupies 0..65535)

__device__ __forceinline__ f32x4 MFMA(u32x4 a, u32x4 b, f32x4 c) {
    return __builtin_amdgcn_mfma_f32_16x16x32_bf16(
        __builtin_bit_cast(bf16x8, a), __builtin_bit_cast(bf16x8, b), c, 0, 0, 0);
}

__device__ __forceinline__ unsigned pk2(float a, float b) {
    __hip_bfloat16 ha = __float2bfloat16(a);
    __hip_bfloat16 hb = __float2bfloat16(b);
    unsigned short sa, sb;
    __builtin_memcpy(&sa, &ha, 2);
    __builtin_memcpy(&sb, &hb, 2);
    return (unsigned)sa | ((unsigned)sb << 16);
}

// B^T tile byte offset for (o 0..255, p 0..31): 128 row-pairs x 128B.
// R7-measured ZERO bank conflicts for this read/write shape.
__device__ __forceinline__ int bbyte(int o, int p) {
    const int rp  = o >> 1;
    const int raw = ((o & 1) << 2) | (p >> 3);
    const int key = (rp ^ (o >> 4)) & 7;
    return rp * 128 + ((raw ^ key) << 4) + ((p & 7) << 1);
}

__global__ __launch_bounds__(512, 4) void argemm_kernel(
    const float* __restrict__ x,
    const int* __restrict__ idx,
    const float* __restrict__ w,
    const float* __restrict__ bias,
    float* __restrict__ out)
{
    __shared__ __align__(16) char lds[81920];  // A panel 64KB | B^T single 16KB

    const int tid = threadIdx.x;
    const int l   = tid & 63;
    const int wid = tid >> 6;        // 0..7: wave owns rows wid*16..+15
    const int g   = l >> 4;          // 0..3 (k-subgroup)
    const int i   = l & 15;          // 0..15

    // XCD-chunked swizzle: logical bit0 = n-half -> the two tiles of one b
    // are adjacent (co-resident, same XCD -> w L2-coincident).
    const unsigned bid     = blockIdx.x;
    const unsigned chunk   = gridDim.x >> 3;
    const unsigned logical = (bid & 7u) * chunk + (bid >> 3);
    const int n0 = (int)(logical & 1u) * 128;
    const int b  = (int)(logical >> 1);

    const int c = idx[b];
    const float* xb = x + (size_t)b * (256 * 256);
    const float* wb = w + (size_t)c * (256 * 256);

    // ---- B staging map (R7 zero-conflict shape): o-quad q, k-quad oct ----
    const int q   = tid & 63;        // cols q*4 .. q*4+3
    const int oct = tid >> 6;        // k-rows oct*4 .. oct*4+3
    const float* wp = wb + (size_t)(oct * 4) * 256 + q * 4;
    int bW[4];
#pragma unroll
    for (int j = 0; j < 4; ++j)
        bW[j] = B_LDS + bbyte(q * 4 + j, oct * 4);

    // ---- fragment read addresses ----
    int bR[16];
#pragma unroll
    for (int n = 0; n < 16; ++n)
        bR[n] = B_LDS + bbyte(n * 16 + i, g * 8);
    const int aRow = (wid * 16 + i) * 512;
    const int aKey = (wid * 16 + i) & 31;

    // ---- single B staging set (2-phase rounds) ----
    f32x4 rb[4];
    auto issueB = [&](int t) {
#pragma unroll
        for (int e = 0; e < 4; ++e)
            rb[e] = *(const f32x4*)(wp + (size_t)t * (BK * 256) + e * 256);
    };
    auto flushB = [&]() {
#pragma unroll
        for (int j = 0; j < 4; ++j) {
            u32x2 pr;                                   // p-run 4: k = oct*4+e
            pr.x = pk2(rb[0][j], rb[1][j]);
            pr.y = pk2(rb[2][j], rb[3][j]);
            *(u32x2*)((char*)lds + bW[j]) = pr;
        }
    };

    // ---- prologue: B(0) loads oldest; A panel staged (nt, sequential) ----
    issueB(0);
    __builtin_amdgcn_sched_barrier(0);

    // A: wave stages rows wid*16..+15, one full 1KB row per instruction.
    {
        const float* xw = xb + (n0 + wid * 16) * 256 + l * 4;
        const int csw = l >> 1;
        const int sub = (l & 1) * 8;
        f32x4 xa[8];
#pragma unroll
        for (int s2 = 0; s2 < 2; ++s2) {
#pragma unroll
            for (int j = 0; j < 8; ++j)
                xa[j] = __builtin_nontemporal_load(
                    (const f32x4*)(xw + (s2 * 8 + j) * 256));
            __builtin_amdgcn_sched_barrier(0);
#pragma unroll
            for (int j = 0; j < 8; ++j) {
                const int r = wid * 16 + s2 * 8 + j;
                u32x2 p;
                p.x = pk2(xa[j].x, xa[j].y);
                p.y = pk2(xa[j].z, xa[j].w);
                *(u32x2*)((char*)lds + r * 512 + ((csw ^ (r & 31)) << 4) + sub) = p;
            }
        }
    }
    flushB();                           // B(0) cvt+write (counted vmcnt wait)
    asm volatile("s_waitcnt lgkmcnt(0)" ::: "memory");
    __builtin_amdgcn_sched_barrier(0);
    __builtin_amdgcn_s_barrier();       // A panel + B(0) visible

    f32x4 acc[16];
#pragma unroll
    for (int n = 0; n < 16; ++n)
        acc[n] = (f32x4){0.f, 0.f, 0.f, 0.f};

    // ---- K loop: 8 two-phase rounds ----
#pragma unroll
    for (int t = 0; t < 8; ++t) {
        if (t < 7) {
            issueB(t + 1);              // in flight across compute(t)
            __builtin_amdgcn_sched_barrier(0);
        }

        const u32x4 af = *(const u32x4*)((const char*)lds + aRow
                                         + (((t * 4 + g) ^ aKey) << 4));
#pragma unroll
        for (int n = 0; n < 16; ++n) {
            const u32x4 bq = *(const u32x4*)((const char*)lds + bR[n]);
            acc[n] = MFMA(af, bq, acc[n]);
        }

        if (t < 7) {
            asm volatile("s_waitcnt lgkmcnt(0)" ::: "memory");  // B(t) reads retired
            __builtin_amdgcn_sched_barrier(0);
            __builtin_amdgcn_s_barrier();
            flushB();                   // overwrite with tile t+1
            asm volatile("s_waitcnt lgkmcnt(0)" ::: "memory");
            __builtin_amdgcn_sched_barrier(0);
            __builtin_amdgcn_s_barrier();                       // B(t+1) visible
        }
    }

    // ---- epilogue: bias + LeakyReLU(0.2), nontemporal f32 store ----
    float biasf[16];
#pragma unroll
    for (int n = 0; n < 16; ++n)
        biasf[n] = bias[n * 16 + i];

    float* ob = out + (size_t)b * (256 * 256);
#pragma unroll
    for (int r = 0; r < 4; ++r) {
        const int row = n0 + wid * 16 + g * 4 + r;
#pragma unroll
        for (int n = 0; n < 16; ++n) {
            float v = acc[n][r] + biasf[n];
            v = (v >= 0.f) ? v : 0.2f * v;
            __builtin_nontemporal_store(v, &ob[row * 256 + n * 16 + i]);
        }
    }
}

extern "C" void kernel_launch(void* const* d_in, const int* in_sizes, int n_in,
                              void* d_out, int out_size, void* d_ws, size_t ws_size,
                              hipStream_t stream) {
    const float* x    = (const float*)d_in[0];
    const int*   idx  = (const int*)d_in[1];
    const float* w    = (const float*)d_in[2];
    const float* bias = (const float*)d_in[3];
    float*       out  = (float*)d_out;
    (void)d_ws; (void)ws_size; (void)n_in; (void)out_size;

    const int B = in_sizes[1];          // 2048
    dim3 grid((unsigned)(B * 2)), block(512);
    hipLaunchKernelGGL(argemm_kernel, grid, block, 0, stream, x, idx, w, bias, out);
}